// Round 4
// baseline (391.513 us; speedup 1.0000x reference)
//
#include <hip/hip_runtime.h>
#include <cstdint>
#include <cstddef>
#include <cstdio>

// ---------------------------------------------------------------------------
// TransformerLayer on MI355X (gfx950), bf16 MFMA everywhere.
// b=2, L=2048, d=1024, d_ff=3072, nh=16, D_HEAD=64.
// Round 4: attention moves to 32x32x16 MFMA (2x FLOP per LDS byte) with
// 32 q-rows/wave (K/V tile reads amortized 2x). GEMMs unchanged.
// ---------------------------------------------------------------------------

typedef unsigned short u16;
typedef __bf16 bf16x8 __attribute__((ext_vector_type(8)));
typedef float  f32x4  __attribute__((ext_vector_type(4)));
typedef float  f32x16 __attribute__((ext_vector_type(16)));

__device__ __forceinline__ u16 f2b(float f) {
  return __builtin_bit_cast(u16, (__bf16)f);
}
__device__ __forceinline__ float b2f(u16 u) {
  return (float)__builtin_bit_cast(__bf16, u);
}

// async global->LDS, 16B per lane. LDS dest must be wave-uniform base + lane*16.
__device__ __forceinline__ void cp16(const u16* g, u16* l) {
  __builtin_amdgcn_global_load_lds(
      (__attribute__((address_space(1))) void*)(uintptr_t)g,
      (__attribute__((address_space(3))) void*)(uintptr_t)l,
      16, 0, 0);
}

// ---------------------------------------------------------------------------
// GEMM: C[M,N] = A[M,K] @ B[N,K]^T  (A row stride = lda, B row stride = K)
// A, B bf16; C fp32 (MODE 0), fp32 + residual (MODE 1), bf16 (MODE 2).
// 128x128 tile, BK=64, 4 waves, 16x16x32 MFMA, XOR-swizzled LDS (r3).
// ---------------------------------------------------------------------------
template <int MODE>
__global__ __launch_bounds__(256) void gemm_bt(
    const u16* __restrict__ A, const u16* __restrict__ B,
    float* __restrict__ Cf, u16* __restrict__ Cb, const float* __restrict__ res,
    int M, int N, int K, int lda)
{
  __shared__ __align__(16) u16 lsA[128 * 64];
  __shared__ __align__(16) u16 lsB[128 * 64];
  const int t = threadIdx.x;
  const int w = t >> 6, lane = t & 63;
  const int wm = (w >> 1) * 64, wn = (w & 1) * 64;
  const int lr = lane & 15, quad = lane >> 4;
  const int cswz = lr & 7;
  const size_t rowA0 = (size_t)blockIdx.x * 128;
  const size_t rowB0 = (size_t)blockIdx.y * 128;

  f32x4 acc[4][4] = {};

  for (int k0 = 0; k0 < K; k0 += 64) {
#pragma unroll
    for (int i = 0; i < 4; ++i) {
      const int id = i * 256 + t;
      const int r = id >> 3;
      const int c = ((id & 7) ^ (r & 7)) * 8;  // swizzled source column
      cp16(A + (rowA0 + r) * lda + k0 + c, lsA + id * 8);
      cp16(B + (rowB0 + r) * (size_t)K + k0 + c, lsB + id * 8);
    }
    __syncthreads();
#pragma unroll
    for (int ks = 0; ks < 2; ++ks) {
      const int co = ((ks * 4 + quad) ^ cswz) * 8;
      bf16x8 af[4], bfr[4];
#pragma unroll
      for (int i = 0; i < 4; ++i) {
        af[i]  = *(const bf16x8*)(lsA + (wm + i * 16 + lr) * 64 + co);
        bfr[i] = *(const bf16x8*)(lsB + (wn + i * 16 + lr) * 64 + co);
      }
#pragma unroll
      for (int mi = 0; mi < 4; ++mi)
#pragma unroll
        for (int ni = 0; ni < 4; ++ni)
          acc[mi][ni] = __builtin_amdgcn_mfma_f32_16x16x32_bf16(
              af[mi], bfr[ni], acc[mi][ni], 0, 0, 0);
    }
    __syncthreads();
  }

#pragma unroll
  for (int mi = 0; mi < 4; ++mi) {
#pragma unroll
    for (int r = 0; r < 4; ++r) {
      const size_t m = rowA0 + wm + mi * 16 + quad * 4 + r;
#pragma unroll
      for (int ni = 0; ni < 4; ++ni) {
        const size_t n = rowB0 + wn + ni * 16 + lr;
        const size_t o = m * (size_t)N + n;
        const float v = acc[mi][ni][r];
        if (MODE == 0) Cf[o] = v;
        else if (MODE == 1) Cf[o] = v + res[o];
        else Cb[o] = f2b(v);
      }
    }
  }
}

// ---------------------------------------------------------------------------
// RMSNorm: one block per row of 1024; fp32 in, bf16 out.
// ---------------------------------------------------------------------------
__global__ __launch_bounds__(256) void rmsnorm_k(
    const float* __restrict__ x, const float* __restrict__ g, u16* __restrict__ out)
{
  const int row = blockIdx.x;
  const int t = threadIdx.x;
  const float4 a = ((const float4*)(x + (size_t)row * 1024))[t];
  float ss = a.x * a.x + a.y * a.y + a.z * a.z + a.w * a.w;
#pragma unroll
  for (int o = 32; o; o >>= 1) ss += __shfl_xor(ss, o, 64);
  __shared__ float red[4];
  if ((t & 63) == 0) red[t >> 6] = ss;
  __syncthreads();
  ss = red[0] + red[1] + red[2] + red[3];
  const float r = rsqrtf(ss * (1.0f / 1024.0f) + 1e-6f);
  const float4 gg = ((const float4*)g)[t];
  ushort4 o4;
  o4.x = f2b(a.x * gg.x * r);
  o4.y = f2b(a.y * gg.y * r);
  o4.z = f2b(a.z * gg.z * r);
  o4.w = f2b(a.w * gg.w * r);
  ((ushort4*)out)[(size_t)row * 256 + t] = o4;
}

// fp32 -> bf16 weight conversion, 4 elems/thread.
__global__ __launch_bounds__(256) void cvt_bf16_k(
    const float* __restrict__ in, u16* __restrict__ out)
{
  const size_t i = (size_t)blockIdx.x * 256 + threadIdx.x;
  const float4 v = ((const float4*)in)[i];
  ushort4 o4;
  o4.x = f2b(v.x); o4.y = f2b(v.y); o4.z = f2b(v.z); o4.w = f2b(v.w);
  ((ushort4*)out)[i] = o4;
}

// ---------------------------------------------------------------------------
// QKV prep (bf16 input): per (n,h,l) cosine-normalize q,k with
// sqrt(attn_scale[h]); write Q,K as [head][l][64] bf16, V transposed as
// [head][e][L] bf16. Grid (L/64, nh, n), block 256.
// ---------------------------------------------------------------------------
__global__ __launch_bounds__(256) void qkv_prep_k(
    const u16* __restrict__ qkv, const float* __restrict__ attn_scale,
    u16* __restrict__ Qb, u16* __restrict__ Kb, u16* __restrict__ Vt)
{
  const int l0 = blockIdx.x * 64;
  const int h  = blockIdx.y;
  const int nb = blockIdx.z;
  const int t = threadIdx.x, w = t >> 6, lane = t & 63;
  __shared__ float lsV[64][65];  // +1 pad: conflict-free transposed reads
  const float sq = sqrtf(attn_scale[h]);
  const int head = nb * 16 + h;
#pragma unroll 4
  for (int i = 0; i < 16; ++i) {
    const int lrow = i * 4 + w;
    const int l = l0 + lrow;
    const u16* base = qkv + ((size_t)nb * 2048 + l) * 3072 + h * 64 + lane;
    const float qv = b2f(base[0]);
    const float kv = b2f(base[1024]);
    const float vv = b2f(base[2048]);
    float ssq = qv * qv, ssk = kv * kv;
#pragma unroll
    for (int o = 32; o; o >>= 1) {
      ssq += __shfl_xor(ssq, o, 64);
      ssk += __shfl_xor(ssk, o, 64);
    }
    const size_t gb = ((size_t)head * 2048 + l) * 64 + lane;
    Qb[gb] = f2b(qv * sq * rsqrtf(ssq + 1e-6f));
    Kb[gb] = f2b(kv * sq * rsqrtf(ssk + 1e-6f));
    lsV[lrow][lane] = vv;
  }
  __syncthreads();
  const int e = t >> 2, p = t & 3;
  union { u16 s[16]; uint4 v[2]; } tmp;
#pragma unroll
  for (int j = 0; j < 16; ++j) tmp.s[j] = f2b(lsV[p * 16 + j][e]);
  u16* dst = Vt + ((size_t)head * 64 + e) * 2048 + l0 + p * 16;
  *(uint4*)dst = tmp.v[0];
  *(uint4*)(dst + 8) = tmp.v[1];
}

// ---------------------------------------------------------------------------
// Attention, round 4: 32x32x16 MFMA, 32 q-rows/wave (block = 128 q-rows).
// Cosine-norm bounds scores to [-10,10] -> softmax without max tracking.
// Per k-tile of 64: S = Q(32x64)·K^T via 2ni x 4kc MFMAs (Q in regs),
// exp -> P (swizzled LDS, wave-private), O += P·V via 4kc x 2ei MFMAs.
// 32x32x16 layouts: A[m=lane&31][k=(lane>>5)*8+j]; B[k=(lane>>5)*8+j][n=lane&31];
// C/D: col=lane&31, row=(r&3)+8*(r>>2)+4*(lane>>5)  [m74/m101].
// LDS: 2*(8K+8K) dbuf + 4*4K P = 48 KB. Grid (L/128, n*nh) = (16, 32).
// All tiles XOR-swizzled: 16B chunk c of row r at c^(r&7) (8 lanes/chunk-group
// per b128 access = conflict-free floor; verified pattern-by-pattern).
// ---------------------------------------------------------------------------
__global__ __launch_bounds__(256) void attn_k(
    const u16* __restrict__ Qb, const u16* __restrict__ Kb,
    const u16* __restrict__ Vt, u16* __restrict__ O)
{
  const int l0 = blockIdx.x * 128;
  const int head = blockIdx.y;
  const int nb = head >> 4, h = head & 15;
  const int t = threadIdx.x, w = t >> 6, lane = t & 63;
  const int lm = lane & 31, h2 = lane >> 5;
  __shared__ __align__(16) u16 lsK[2][64 * 64];
  __shared__ __align__(16) u16 lsV[2][64 * 64];
  __shared__ __align__(16) u16 lsP[4][32 * 64];
  u16* myP = lsP[w];
  const size_t hb = (size_t)head << 17;  // head * 2048 * 64

  // staging: thread t owns LDS chunk t (row t>>3, slot t&7); loads global
  // chunk (t&7)^(row&7). Identical to round 3.
  const int sr = t >> 3;
  const int sc = ((t & 7) ^ (sr & 7)) * 8;
  const u16* Kg = Kb + hb + (size_t)sr * 64 + sc;
  const u16* Vg = Vt + hb + (size_t)sr * 2048 + sc;

  // Q fragments (A-operand), 32 rows per wave, held in registers.
  const int qrow = l0 + w * 32 + lm;
  const u16* qp = Qb + hb + (size_t)qrow * 64 + h2 * 8;
  bf16x8 qf[4];
#pragma unroll
  for (int c = 0; c < 4; ++c) qf[c] = *(const bf16x8*)(qp + c * 16);

  f32x16 oacc[2] = {};
  float rsv[16];
#pragma unroll
  for (int r = 0; r < 16; ++r) rsv[r] = 0.f;

  // prologue: stage tile 0 into buf 0
  cp16(Kg, lsK[0] + t * 8);
  cp16(Kg + 32 * 64, lsK[0] + 32 * 64 + t * 8);
  cp16(Vg, lsV[0] + t * 8);
  cp16(Vg + 32 * 2048, lsV[0] + 32 * 64 + t * 8);

  int cur = 0;
  for (int k0 = 0; k0 < 2048; k0 += 64) {
    __syncthreads();  // buf[cur] staged; alt buf's readers done
    if (k0 + 64 < 2048) {
      const int nxt = cur ^ 1;
      const u16* Kn = Kg + (size_t)(k0 + 64) * 64;
      const u16* Vn = Vg + (k0 + 64);
      cp16(Kn, lsK[nxt] + t * 8);
      cp16(Kn + 32 * 64, lsK[nxt] + 32 * 64 + t * 8);
      cp16(Vn, lsV[nxt] + t * 8);
      cp16(Vn + 32 * 2048, lsV[nxt] + 32 * 64 + t * 8);
    }
    const u16* kb = lsK[cur];
    const u16* vb = lsV[cur];

    // S = Q·K^T (32 q x 64 k per wave), exp -> P
#pragma unroll
    for (int ni = 0; ni < 2; ++ni) {
      const int krow = ni * 32 + lm;
      const int kswz = krow & 7;
      f32x16 s = {};
#pragma unroll
      for (int c = 0; c < 4; ++c) {
        const bf16x8 bk = *(const bf16x8*)(kb + krow * 64 + (((c * 2 + h2) ^ kswz) << 3));
        s = __builtin_amdgcn_mfma_f32_32x32x16_bf16(qf[c], bk, s, 0, 0, 0);
      }
      const int pc = ni * 4 + (lm >> 3);
#pragma unroll
      for (int r = 0; r < 16; ++r) {
        const float p = __expf(s[r]);
        rsv[r] += p;
        const int q2 = (r & 3) + 8 * (r >> 2) + 4 * h2;
        myP[q2 * 64 + ((pc ^ (q2 & 7)) << 3) + (lm & 7)] = f2b(p);
      }
    }
    asm volatile("" ::: "memory");  // order P writes before P reads (same wave)
    // O += P·V  (A = P from LDS, B = V^T from staged Vt tile)
#pragma unroll
    for (int kc = 0; kc < 4; ++kc) {
      const bf16x8 ap = *(const bf16x8*)(myP + lm * 64 + (((kc * 2 + h2) ^ (lm & 7)) << 3));
#pragma unroll
      for (int ei = 0; ei < 2; ++ei) {
        const int vrow = ei * 32 + lm;
        const bf16x8 bv = *(const bf16x8*)(vb + vrow * 64 + (((kc * 2 + h2) ^ (vrow & 7)) << 3));
        oacc[ei] = __builtin_amdgcn_mfma_f32_32x32x16_bf16(ap, bv, oacc[ei], 0, 0, 0);
      }
    }
    asm volatile("" ::: "memory");  // WAR: P reads done before next-iter writes
    cur ^= 1;
  }

  // rowsum: reduce across the 32 lanes of each half (cols 0..63 already
  // accumulated via both ni); xor 1..16 stays within the 32-lane half.
#pragma unroll
  for (int r = 0; r < 16; ++r) {
    float v = rsv[r];
    v += __shfl_xor(v, 1, 64);
    v += __shfl_xor(v, 2, 64);
    v += __shfl_xor(v, 4, 64);
    v += __shfl_xor(v, 8, 64);
    v += __shfl_xor(v, 16, 64);
    rsv[r] = 1.0f / v;
  }
  // O write: [n][l][d] bf16; l = l0 + w*32 + q2, col = h*64 + ei*32 + lm
#pragma unroll
  for (int r = 0; r < 16; ++r) {
    const int q2 = (r & 3) + 8 * (r >> 2) + 4 * h2;
    const int l = l0 + w * 32 + q2;
    u16* ob = O + ((size_t)nb * 2048 + l) * 1024 + h * 64;
#pragma unroll
    for (int ei = 0; ei < 2; ++ei)
      ob[ei * 32 + lm] = f2b(oacc[ei][r] * rsv[r]);
  }
}

// ---------------------------------------------------------------------------
// SwiGLU, in-place on u[4096][6144] bf16: u[:, :3072] = a * silu(g).
// ---------------------------------------------------------------------------
__global__ __launch_bounds__(256) void swiglu_k(u16* __restrict__ u)
{
  const unsigned j = ((unsigned)blockIdx.x * 256 + threadIdx.x) * 8;
  const unsigned row = j / 3072u, col = j % 3072u;
  u16* ap = u + (size_t)row * 6144 + col;
  union { u16 s[8]; uint4 v; } a, g, hh;
  a.v = *(const uint4*)ap;
  g.v = *(const uint4*)(ap + 3072);
#pragma unroll
  for (int i = 0; i < 8; ++i) {
    const float av = b2f(a.s[i]);
    const float gv = b2f(g.s[i]);
    hh.s[i] = f2b(av * (gv / (1.0f + __expf(-gv))));
  }
  *(uint4*)ap = hh.v;
}

// ---------------------------------------------------------------------------
// Workspace layout (bytes).
// ---------------------------------------------------------------------------
static constexpr size_t WQKV_B = 0;                            // 3072*1024*2
static constexpr size_t WOUT_B = WQKV_B + 6291456;             // 1024*1024*2
static constexpr size_t WUP_B  = WOUT_B + 2097152;             // 6144*1024*2
static constexpr size_t WDN_B  = WUP_B + 12582912;             // 1024*3072*2
static constexpr size_t XN_B   = WDN_B + 6291456;              // 4096*1024*2
static constexpr size_t Q_B    = XN_B + 8388608;               // 32*2048*64*2
static constexpr size_t K_B    = Q_B + 8388608;
static constexpr size_t VT_B   = K_B + 8388608;
static constexpr size_t O_B    = VT_B + 8388608;               // 4096*1024*2
static constexpr size_t BIG_B  = O_B + 8388608;                // qkv bf16 / u bf16
static constexpr size_t WS_NEED = BIG_B + 50331648;            // = 119537664

extern "C" void kernel_launch(void* const* d_in, const int* in_sizes, int n_in,
                              void* d_out, int out_size, void* d_ws, size_t ws_size,
                              hipStream_t stream)
{
  (void)in_sizes; (void)n_in; (void)out_size;
  if (ws_size < WS_NEED) {
    fprintf(stderr, "kernel_launch: ws_size %zu < required %zu\n", ws_size, WS_NEED);
    return;
  }
  const float* x          = (const float*)d_in[0];
  const float* norm_scale = (const float*)d_in[2];
  const float* w_qkv      = (const float*)d_in[3];
  const float* attn_scale = (const float*)d_in[4];
  const float* w_out      = (const float*)d_in[5];
  const float* ff_scale   = (const float*)d_in[6];
  const float* w_up       = (const float*)d_in[7];
  const float* w_down     = (const float*)d_in[8];
  float* out = (float*)d_out;
  char* ws = (char*)d_ws;

  u16* wqkv_b = (u16*)(ws + WQKV_B);
  u16* wout_b = (u16*)(ws + WOUT_B);
  u16* wup_b  = (u16*)(ws + WUP_B);
  u16* wdn_b  = (u16*)(ws + WDN_B);
  u16* xn     = (u16*)(ws + XN_B);
  u16* Qb     = (u16*)(ws + Q_B);
  u16* Kb     = (u16*)(ws + K_B);
  u16* Vtb    = (u16*)(ws + VT_B);
  u16* Ob     = (u16*)(ws + O_B);
  u16* qkvb   = (u16*)(ws + BIG_B);  // qkv bf16 (25 MB), later reused for u
  u16* ub     = (u16*)(ws + BIG_B);

  // weights fp32 -> bf16
  cvt_bf16_k<<<3072, 256, 0, stream>>>(w_qkv, wqkv_b);
  cvt_bf16_k<<<1024, 256, 0, stream>>>(w_out, wout_b);
  cvt_bf16_k<<<6144, 256, 0, stream>>>(w_up,  wup_b);
  cvt_bf16_k<<<3072, 256, 0, stream>>>(w_down, wdn_b);

  // xn = rmsnorm(x)
  rmsnorm_k<<<4096, 256, 0, stream>>>(x, norm_scale, xn);
  // qkv = xn @ w_qkv^T  (bf16 out)
  gemm_bt<2><<<dim3(32, 24), 256, 0, stream>>>(xn, wqkv_b, nullptr, qkvb, nullptr,
                                               4096, 3072, 1024, 1024);
  // q/k cosine norm + head-major layouts + V transpose
  qkv_prep_k<<<dim3(32, 16, 2), 256, 0, stream>>>(qkvb, attn_scale, Qb, Kb, Vtb);
  // attention -> O bf16 [n][l][d]
  attn_k<<<dim3(16, 32), 256, 0, stream>>>(Qb, Kb, Vtb, Ob);
  // x1 = O @ w_out^T + x  -> d_out (fp32)
  gemm_bt<1><<<dim3(32, 8), 256, 0, stream>>>(Ob, wout_b, out, nullptr, x,
                                              4096, 1024, 1024, 1024);
  // xn = rmsnorm(x1)
  rmsnorm_k<<<4096, 256, 0, stream>>>(out, ff_scale, xn);
  // u = xn @ w_up^T  (bf16 out, 4096x6144)  -- overwrites qkvb region
  gemm_bt<2><<<dim3(32, 48), 256, 0, stream>>>(xn, wup_b, nullptr, ub, nullptr,
                                               4096, 6144, 1024, 1024);
  // h = a * silu(g), in-place into u[:, :3072]
  swiglu_k<<<6144, 256, 0, stream>>>(ub);
  // out = h @ w_down^T + x1  (in-place residual on d_out)
  gemm_bt<1><<<dim3(32, 8), 256, 0, stream>>>(ub, wdn_b, out, nullptr, out,
                                              4096, 1024, 3072, 6144);
}

// Round 5
// 368.480 us; speedup vs baseline: 1.0625x; 1.0625x over previous
//
#include <hip/hip_runtime.h>
#include <cstdint>
#include <cstddef>
#include <cstdio>

// ---------------------------------------------------------------------------
// TransformerLayer on MI355X (gfx950), bf16 MFMA everywhere.
// b=2, L=2048, d=1024, d_ff=3072, nh=16, D_HEAD=64.
// Round 5: attention computes S^T = K·Q^T so the exp'd P tile feeds the PV
// MFMA directly from registers (C-layout of S^T == B-operand layout of
// 16x16x16 MFMA). No P LDS round-trip. GEMMs gain a BN=64 variant for the
// occupancy-starved N=1024 projections.
// ---------------------------------------------------------------------------

typedef unsigned short u16;
typedef __bf16 bf16x8 __attribute__((ext_vector_type(8)));
typedef short  s16x4  __attribute__((ext_vector_type(4)));
typedef float  f32x4  __attribute__((ext_vector_type(4)));

__device__ __forceinline__ u16 f2b(float f) {
  return __builtin_bit_cast(u16, (__bf16)f);
}
__device__ __forceinline__ float b2f(u16 u) {
  return (float)__builtin_bit_cast(__bf16, u);
}

// async global->LDS, 16B per lane. LDS dest must be wave-uniform base + lane*16.
__device__ __forceinline__ void cp16(const u16* g, u16* l) {
  __builtin_amdgcn_global_load_lds(
      (__attribute__((address_space(1))) void*)(uintptr_t)g,
      (__attribute__((address_space(3))) void*)(uintptr_t)l,
      16, 0, 0);
}

// ---------------------------------------------------------------------------
// GEMM: C[M,N] = A[M,K] @ B[N,K]^T  (A row stride = lda, B row stride = K)
// A, B bf16; C fp32 (MODE 0), fp32 + residual (MODE 1), bf16 (MODE 2).
// 128xBN tile (BN=128 or 64), BK=64, 4 waves, 16x16x32 MFMA, XOR-swizzled LDS.
// BN=64 doubles the grid for N=1024 shapes (was 1 block/CU).
// ---------------------------------------------------------------------------
template <int MODE, int BN>
__global__ __launch_bounds__(256) void gemm_bt(
    const u16* __restrict__ A, const u16* __restrict__ B,
    float* __restrict__ Cf, u16* __restrict__ Cb, const float* __restrict__ res,
    int M, int N, int K, int lda)
{
  constexpr int NI = BN / 32;          // acc cols per wave
  __shared__ __align__(16) u16 lsA[128 * 64];
  __shared__ __align__(16) u16 lsB[BN * 64];
  const int t = threadIdx.x;
  const int w = t >> 6, lane = t & 63;
  const int wm = (w >> 1) * 64, wn = (w & 1) * (BN / 2);
  const int lr = lane & 15, quad = lane >> 4;
  const int cswz = lr & 7;
  const size_t rowA0 = (size_t)blockIdx.x * 128;
  const size_t rowB0 = (size_t)blockIdx.y * BN;

  f32x4 acc[4][NI] = {};

  for (int k0 = 0; k0 < K; k0 += 64) {
#pragma unroll
    for (int i = 0; i < 4; ++i) {
      const int id = i * 256 + t;
      const int r = id >> 3;
      const int c = ((id & 7) ^ (r & 7)) * 8;  // swizzled source column
      cp16(A + (rowA0 + r) * lda + k0 + c, lsA + id * 8);
    }
#pragma unroll
    for (int i = 0; i < BN / 32; ++i) {
      const int id = i * 256 + t;
      const int r = id >> 3;
      const int c = ((id & 7) ^ (r & 7)) * 8;
      cp16(B + (rowB0 + r) * (size_t)K + k0 + c, lsB + id * 8);
    }
    __syncthreads();
#pragma unroll
    for (int ks = 0; ks < 2; ++ks) {
      const int co = ((ks * 4 + quad) ^ cswz) * 8;
      bf16x8 af[4], bfr[NI];
#pragma unroll
      for (int i = 0; i < 4; ++i)
        af[i] = *(const bf16x8*)(lsA + (wm + i * 16 + lr) * 64 + co);
#pragma unroll
      for (int i = 0; i < NI; ++i)
        bfr[i] = *(const bf16x8*)(lsB + (wn + i * 16 + lr) * 64 + co);
#pragma unroll
      for (int mi = 0; mi < 4; ++mi)
#pragma unroll
        for (int ni = 0; ni < NI; ++ni)
          acc[mi][ni] = __builtin_amdgcn_mfma_f32_16x16x32_bf16(
              af[mi], bfr[ni], acc[mi][ni], 0, 0, 0);
    }
    __syncthreads();
  }

#pragma unroll
  for (int mi = 0; mi < 4; ++mi) {
#pragma unroll
    for (int r = 0; r < 4; ++r) {
      const size_t m = rowA0 + wm + mi * 16 + quad * 4 + r;
#pragma unroll
      for (int ni = 0; ni < NI; ++ni) {
        const size_t n = rowB0 + wn + ni * 16 + lr;
        const size_t o = m * (size_t)N + n;
        const float v = acc[mi][ni][r];
        if (MODE == 0) Cf[o] = v;
        else if (MODE == 1) Cf[o] = v + res[o];
        else Cb[o] = f2b(v);
      }
    }
  }
}

// ---------------------------------------------------------------------------
// RMSNorm: one block per row of 1024; fp32 in, bf16 out.
// ---------------------------------------------------------------------------
__global__ __launch_bounds__(256) void rmsnorm_k(
    const float* __restrict__ x, const float* __restrict__ g, u16* __restrict__ out)
{
  const int row = blockIdx.x;
  const int t = threadIdx.x;
  const float4 a = ((const float4*)(x + (size_t)row * 1024))[t];
  float ss = a.x * a.x + a.y * a.y + a.z * a.z + a.w * a.w;
#pragma unroll
  for (int o = 32; o; o >>= 1) ss += __shfl_xor(ss, o, 64);
  __shared__ float red[4];
  if ((t & 63) == 0) red[t >> 6] = ss;
  __syncthreads();
  ss = red[0] + red[1] + red[2] + red[3];
  const float r = rsqrtf(ss * (1.0f / 1024.0f) + 1e-6f);
  const float4 gg = ((const float4*)g)[t];
  ushort4 o4;
  o4.x = f2b(a.x * gg.x * r);
  o4.y = f2b(a.y * gg.y * r);
  o4.z = f2b(a.z * gg.z * r);
  o4.w = f2b(a.w * gg.w * r);
  ((ushort4*)out)[(size_t)row * 256 + t] = o4;
}

// fp32 -> bf16 weight conversion, 4 elems/thread.
__global__ __launch_bounds__(256) void cvt_bf16_k(
    const float* __restrict__ in, u16* __restrict__ out)
{
  const size_t i = (size_t)blockIdx.x * 256 + threadIdx.x;
  const float4 v = ((const float4*)in)[i];
  ushort4 o4;
  o4.x = f2b(v.x); o4.y = f2b(v.y); o4.z = f2b(v.z); o4.w = f2b(v.w);
  ((ushort4*)out)[i] = o4;
}

// ---------------------------------------------------------------------------
// QKV prep (bf16 input): per (n,h,l) cosine-normalize q,k with
// sqrt(attn_scale[h]); write Q,K as [head][l][64] bf16, V transposed as
// [head][e][L] bf16. Grid (L/64, nh, n), block 256.
// ---------------------------------------------------------------------------
__global__ __launch_bounds__(256) void qkv_prep_k(
    const u16* __restrict__ qkv, const float* __restrict__ attn_scale,
    u16* __restrict__ Qb, u16* __restrict__ Kb, u16* __restrict__ Vt)
{
  const int l0 = blockIdx.x * 64;
  const int h  = blockIdx.y;
  const int nb = blockIdx.z;
  const int t = threadIdx.x, w = t >> 6, lane = t & 63;
  __shared__ float lsV[64][65];  // +1 pad: conflict-free transposed reads
  const float sq = sqrtf(attn_scale[h]);
  const int head = nb * 16 + h;
#pragma unroll 4
  for (int i = 0; i < 16; ++i) {
    const int lrow = i * 4 + w;
    const int l = l0 + lrow;
    const u16* base = qkv + ((size_t)nb * 2048 + l) * 3072 + h * 64 + lane;
    const float qv = b2f(base[0]);
    const float kv = b2f(base[1024]);
    const float vv = b2f(base[2048]);
    float ssq = qv * qv, ssk = kv * kv;
#pragma unroll
    for (int o = 32; o; o >>= 1) {
      ssq += __shfl_xor(ssq, o, 64);
      ssk += __shfl_xor(ssk, o, 64);
    }
    const size_t gb = ((size_t)head * 2048 + l) * 64 + lane;
    Qb[gb] = f2b(qv * sq * rsqrtf(ssq + 1e-6f));
    Kb[gb] = f2b(kv * sq * rsqrtf(ssk + 1e-6f));
    lsV[lrow][lane] = vv;
  }
  __syncthreads();
  const int e = t >> 2, p = t & 3;
  union { u16 s[16]; uint4 v[2]; } tmp;
#pragma unroll
  for (int j = 0; j < 16; ++j) tmp.s[j] = f2b(lsV[p * 16 + j][e]);
  u16* dst = Vt + ((size_t)head * 64 + e) * 2048 + l0 + p * 16;
  *(uint4*)dst = tmp.v[0];
  *(uint4*)(dst + 8) = tmp.v[1];
}

// ---------------------------------------------------------------------------
// Attention, round 5: no P LDS round-trip.
// S^T = K·Q^T via 16x16x32 (A=K-frag, B=Q-frag). S^T C-layout: lane holds
// col q=lane&15, rows kpos=quad*4+r. That IS the B-operand layout of
// 16x16x16 MFMA (lane n=lane&15, k=quad*4+j). So exp(s)->bf16 pack feeds PV
// directly: O^T[e][q] += V^T-frag (A, from LDS b64) x P^T-frag (B, registers).
// Rowsum: per-lane scalar (lane's outputs all share q), 2 shuffles at end.
// Block = 64 q (4 waves x 16); k-tiles of 64 double-buffered in LDS.
// LDS: 2*(8K+8K) = 32 KB -> 5 blocks/CU capacity; grid (32,32) = 4/CU.
// Scores bounded [-10,10] by cosine norm -> no max-tracking needed.
// ---------------------------------------------------------------------------
__global__ __launch_bounds__(256) void attn_k(
    const u16* __restrict__ Qb, const u16* __restrict__ Kb,
    const u16* __restrict__ Vt, u16* __restrict__ O)
{
  const int l0 = blockIdx.x * 64;
  const int head = blockIdx.y;
  const int nb = head >> 4, h = head & 15;
  const int t = threadIdx.x, w = t >> 6, lane = t & 63;
  const int lr = lane & 15, quad = lane >> 4;
  __shared__ __align__(16) u16 lsK[2][64 * 64];
  __shared__ __align__(16) u16 lsV[2][64 * 64];
  const size_t hb = (size_t)head << 17;  // head * 2048 * 64

  // staging: thread t owns LDS chunk t (row t>>3, slot t&7); loads global
  // chunk (t&7)^(row&7) so logical chunk lc of row r lives at lc^(r&7).
  const int sr = t >> 3;
  const int sc = ((t & 7) ^ (sr & 7)) * 8;
  const u16* Kg = Kb + hb + (size_t)sr * 64 + sc;
  const u16* Vg = Vt + hb + (size_t)sr * 2048 + sc;

  // Q fragments (B-operand of S^T): lane holds q=lr, e=quad*8+j (+32).
  const int qrow = l0 + w * 16 + lr;
  const u16* qp = Qb + hb + (size_t)qrow * 64 + quad * 8;
  const bf16x8 qf0 = *(const bf16x8*)qp;
  const bf16x8 qf1 = *(const bf16x8*)(qp + 32);

  f32x4 ot[4] = {};   // O^T acc: ot[ei][r] = O^T[e=ei*16+quad*4+r][q=lr]
  float rs = 0.f;     // partial rowsum for q=lr over this lane's kpos

  // prologue: stage tile 0 into buf 0
  cp16(Kg, lsK[0] + t * 8);
  cp16(Kg + 32 * 64, lsK[0] + 32 * 64 + t * 8);
  cp16(Vg, lsV[0] + t * 8);
  cp16(Vg + 32 * 2048, lsV[0] + 32 * 64 + t * 8);

  int cur = 0;
  for (int k0 = 0; k0 < 2048; k0 += 64) {
    __syncthreads();  // buf[cur] staged; alt buf's readers done
    if (k0 + 64 < 2048) {
      const int nxt = cur ^ 1;
      const u16* Kn = Kg + (size_t)(k0 + 64) * 64;
      const u16* Vn = Vg + (k0 + 64);
      cp16(Kn, lsK[nxt] + t * 8);
      cp16(Kn + 32 * 64, lsK[nxt] + 32 * 64 + t * 8);
      cp16(Vn, lsV[nxt] + t * 8);
      cp16(Vn + 32 * 2048, lsV[nxt] + 32 * 64 + t * 8);
    }
    const u16* kb = lsK[cur];
    const u16* vb = lsV[cur];

#pragma unroll
    for (int kt = 0; kt < 4; ++kt) {
      // S^T tile (16 kpos x 16 q): A = K rows kt*16+lr, e-chunks 0/1.
      const int krow = (kt * 16 + lr) * 64;
      const int kswz = lr & 7;
      const bf16x8 a0 = *(const bf16x8*)(kb + krow + ((quad ^ kswz) << 3));
      const bf16x8 a1 = *(const bf16x8*)(kb + krow + (((4 + quad) ^ kswz) << 3));
      f32x4 s = {};
      s = __builtin_amdgcn_mfma_f32_16x16x32_bf16(a0, qf0, s, 0, 0, 0);
      s = __builtin_amdgcn_mfma_f32_16x16x32_bf16(a1, qf1, s, 0, 0, 0);
      // exp in registers -> P^T fragment (B-operand of 16x16x16, k=quad*4+j)
      s16x4 pf;
#pragma unroll
      for (int r = 0; r < 4; ++r) {
        const float p = __expf(s[r]);
        rs += p;
        pf[r] = (short)f2b(p);
      }
      // O^T += V^T-frag · P^T-frag  (A: lane m=e=lr(+16ei), k=quad*4+j)
      const int vc = kt * 2 + (quad >> 1);       // logical 16B chunk
      const int vh = (quad & 1) * 4;             // 8B half within chunk
#pragma unroll
      for (int ei = 0; ei < 4; ++ei) {
        const int vrow = ei * 16 + lr;
        const s16x4 vf = *(const s16x4*)(vb + vrow * 64 + ((vc ^ (vrow & 7)) << 3) + vh);
        ot[ei] = __builtin_amdgcn_mfma_f32_16x16x16bf16_1k(vf, pf, ot[ei], 0, 0, 0);
      }
    }
    cur ^= 1;
  }

  // rowsum for q=lr: reduce across the 4 quads (lanes lr, lr+16, lr+32, lr+48)
  rs += __shfl_xor(rs, 16, 64);
  rs += __shfl_xor(rs, 32, 64);
  const float inv = 1.0f / rs;

  // O write: O[n][l][d], row l = l0+w*16+lr, cols h*64 + ei*16 + quad*4 + r.
  u16* ob = O + ((size_t)nb * 2048 + l0 + w * 16 + lr) * 1024 + h * 64 + quad * 4;
#pragma unroll
  for (int ei = 0; ei < 4; ++ei) {
    ushort4 o4;
    o4.x = f2b(ot[ei][0] * inv);
    o4.y = f2b(ot[ei][1] * inv);
    o4.z = f2b(ot[ei][2] * inv);
    o4.w = f2b(ot[ei][3] * inv);
    *(ushort4*)(ob + ei * 16) = o4;
  }
}

// ---------------------------------------------------------------------------
// SwiGLU, in-place on u[4096][6144] bf16: u[:, :3072] = a * silu(g).
// ---------------------------------------------------------------------------
__global__ __launch_bounds__(256) void swiglu_k(u16* __restrict__ u)
{
  const unsigned j = ((unsigned)blockIdx.x * 256 + threadIdx.x) * 8;
  const unsigned row = j / 3072u, col = j % 3072u;
  u16* ap = u + (size_t)row * 6144 + col;
  union { u16 s[8]; uint4 v; } a, g, hh;
  a.v = *(const uint4*)ap;
  g.v = *(const uint4*)(ap + 3072);
#pragma unroll
  for (int i = 0; i < 8; ++i) {
    const float av = b2f(a.s[i]);
    const float gv = b2f(g.s[i]);
    hh.s[i] = f2b(av * (gv / (1.0f + __expf(-gv))));
  }
  *(uint4*)ap = hh.v;
}

// ---------------------------------------------------------------------------
// Workspace layout (bytes).
// ---------------------------------------------------------------------------
static constexpr size_t WQKV_B = 0;                            // 3072*1024*2
static constexpr size_t WOUT_B = WQKV_B + 6291456;             // 1024*1024*2
static constexpr size_t WUP_B  = WOUT_B + 2097152;             // 6144*1024*2
static constexpr size_t WDN_B  = WUP_B + 12582912;             // 1024*3072*2
static constexpr size_t XN_B   = WDN_B + 6291456;              // 4096*1024*2
static constexpr size_t Q_B    = XN_B + 8388608;               // 32*2048*64*2
static constexpr size_t K_B    = Q_B + 8388608;
static constexpr size_t VT_B   = K_B + 8388608;
static constexpr size_t O_B    = VT_B + 8388608;               // 4096*1024*2
static constexpr size_t BIG_B  = O_B + 8388608;                // qkv bf16 / u bf16
static constexpr size_t WS_NEED = BIG_B + 50331648;            // = 119537664

extern "C" void kernel_launch(void* const* d_in, const int* in_sizes, int n_in,
                              void* d_out, int out_size, void* d_ws, size_t ws_size,
                              hipStream_t stream)
{
  (void)in_sizes; (void)n_in; (void)out_size;
  if (ws_size < WS_NEED) {
    fprintf(stderr, "kernel_launch: ws_size %zu < required %zu\n", ws_size, WS_NEED);
    return;
  }
  const float* x          = (const float*)d_in[0];
  const float* norm_scale = (const float*)d_in[2];
  const float* w_qkv      = (const float*)d_in[3];
  const float* attn_scale = (const float*)d_in[4];
  const float* w_out      = (const float*)d_in[5];
  const float* ff_scale   = (const float*)d_in[6];
  const float* w_up       = (const float*)d_in[7];
  const float* w_down     = (const float*)d_in[8];
  float* out = (float*)d_out;
  char* ws = (char*)d_ws;

  u16* wqkv_b = (u16*)(ws + WQKV_B);
  u16* wout_b = (u16*)(ws + WOUT_B);
  u16* wup_b  = (u16*)(ws + WUP_B);
  u16* wdn_b  = (u16*)(ws + WDN_B);
  u16* xn     = (u16*)(ws + XN_B);
  u16* Qb     = (u16*)(ws + Q_B);
  u16* Kb     = (u16*)(ws + K_B);
  u16* Vtb    = (u16*)(ws + VT_B);
  u16* Ob     = (u16*)(ws + O_B);
  u16* qkvb   = (u16*)(ws + BIG_B);  // qkv bf16 (25 MB), later reused for u
  u16* ub     = (u16*)(ws + BIG_B);

  // weights fp32 -> bf16
  cvt_bf16_k<<<3072, 256, 0, stream>>>(w_qkv, wqkv_b);
  cvt_bf16_k<<<1024, 256, 0, stream>>>(w_out, wout_b);
  cvt_bf16_k<<<6144, 256, 0, stream>>>(w_up,  wup_b);
  cvt_bf16_k<<<3072, 256, 0, stream>>>(w_down, wdn_b);

  // xn = rmsnorm(x)
  rmsnorm_k<<<4096, 256, 0, stream>>>(x, norm_scale, xn);
  // qkv = xn @ w_qkv^T  (bf16 out)
  gemm_bt<2, 128><<<dim3(32, 24), 256, 0, stream>>>(xn, wqkv_b, nullptr, qkvb,
                                                    nullptr, 4096, 3072, 1024, 1024);
  // q/k cosine norm + head-major layouts + V transpose
  qkv_prep_k<<<dim3(32, 16, 2), 256, 0, stream>>>(qkvb, attn_scale, Qb, Kb, Vtb);
  // attention -> O bf16 [n][l][d]
  attn_k<<<dim3(32, 32), 256, 0, stream>>>(Qb, Kb, Vtb, Ob);
  // x1 = O @ w_out^T + x  -> d_out (fp32); BN=64 for occupancy (N=1024)
  gemm_bt<1, 64><<<dim3(32, 16), 256, 0, stream>>>(Ob, wout_b, out, nullptr, x,
                                                   4096, 1024, 1024, 1024);
  // xn = rmsnorm(x1)
  rmsnorm_k<<<4096, 256, 0, stream>>>(out, ff_scale, xn);
  // u = xn @ w_up^T  (bf16 out, 4096x6144)  -- overwrites qkvb region
  gemm_bt<2, 128><<<dim3(32, 48), 256, 0, stream>>>(xn, wup_b, nullptr, ub, nullptr,
                                                    4096, 6144, 1024, 1024);
  // h = a * silu(g), in-place into u[:, :3072]
  swiglu_k<<<6144, 256, 0, stream>>>(ub);
  // out = h @ w_down^T + x1  (in-place residual on d_out); BN=64
  gemm_bt<1, 64><<<dim3(32, 16), 256, 0, stream>>>(ub, wdn_b, out, nullptr, out,
                                                   4096, 1024, 3072, 6144);
}